// Round 1
// 1119.430 us; speedup vs baseline: 1.0414x; 1.0414x over previous
//
#include <hip/hip_runtime.h>
#include <math.h>

#define NN 50000
#define NE 400000
#define HD 512
#define EDIM 64
#define H2 1024
#define LDT 72           // padded LDS row stride (ushorts)
#define CAP_SLOT 1200000 // padded edge-slot capacity (>= NE + 16*NN worst pad)
#define CAP_TILE 75000   // CAP_SLOT/16
#define NBLK_SCAN 98     // ceil(NN/512)

typedef short s16x8 __attribute__((ext_vector_type(8)));
typedef float f32x4 __attribute__((ext_vector_type(4)));

__device__ __forceinline__ unsigned short f2bf(float f) {
    union { float f; unsigned u; } v; v.f = f;
    unsigned r = v.u + 0x7fffu + ((v.u >> 16) & 1u);
    return (unsigned short)(r >> 16);
}
__device__ __forceinline__ float bf2f(unsigned short h) {
    union { unsigned u; float f; } v; v.u = ((unsigned)h) << 16;
    return v.f;
}
__device__ __forceinline__ float silu_f(float t) {
    return t / (1.f + __expf(-t));
}

// ---------------- workspace layout (bytes), total ~166.3 MB ----------------
constexpr size_t OFF_AGGR = 0;                        // f32 [NN][512]; DEAD after k_combine
constexpr size_t OFF_H1   = 0;                        // bf16 [NN][1024] (aliases aggr)
constexpr size_t OFF_H    = 102400000;                // bf16 [NN][512]
constexpr size_t OFF_WET  = 153600000;                // bf16 [512][64]
constexpr size_t OFF_W1T  = OFF_WET + 65536;          // bf16 [1024][512]
constexpr size_t OFF_W2T  = OFF_W1T + 1048576;        // bf16 [512][1024]
constexpr size_t OFF_CNT  = OFF_W2T + 1048576;        // int[50000]   (zeroed)
constexpr size_t OFF_B1S  = OFF_CNT + 200000;         // float[1024]  (zeroed)
constexpr size_t OFF_B1Q  = OFF_B1S + 4096;           // float[1024]  (zeroed)
constexpr size_t OFF_B2S  = OFF_B1Q + 4096;           // float[512]   (zeroed)
constexpr size_t OFF_B2Q  = OFF_B2S + 2048;           // float[512]   (zeroed)
constexpr size_t ZERO_BYTES = 200000 + 4096 + 4096 + 2048 + 2048;
constexpr size_t OFF_TEX  = OFF_B2Q + 2048;           // int[50000] tile_excl
constexpr size_t OFF_BSUM = OFF_TEX + 200000;         // int[128]
constexpr size_t OFF_BOFF = OFF_BSUM + 512;           // int[128]
constexpr size_t OFF_T    = OFF_BOFF + 512;           // int[16]
constexpr size_t OFF_CUR  = OFF_T + 64;               // int[50000]
constexpr size_t OFF_NOT  = OFF_CUR + 200000;         // int[75008] node_of_tile
constexpr size_t OFF_SRCP = OFF_NOT + 300032;         // int[CAP_SLOT] (memset 0xFF)
constexpr size_t OFF_EIXP = OFF_SRCP + 4800000;       // int[CAP_SLOT]
constexpr size_t OFF_SC1  = OFF_EIXP + 4800000;       // float[1024]
constexpr size_t OFF_SB1  = OFF_SC1 + 4096;           // float[1024]
constexpr size_t OFF_SC2  = OFF_SB1 + 4096;           // float[512]
constexpr size_t OFF_SB2  = OFF_SC2 + 2048;           // float[512]

// ---------------- weight transpose+convert to bf16 ----------------
__global__ __launch_bounds__(256) void k_convert(const float* __restrict__ We,
    const float* __restrict__ W1, const float* __restrict__ W2,
    unsigned short* __restrict__ wet, unsigned short* __restrict__ w1t,
    unsigned short* __restrict__ w2t) {
    int i = blockIdx.x * 256 + threadIdx.x;
    if (i < 32768) {
        int n = i >> 6, k = i & 63;
        wet[i] = f2bf(We[k * HD + n]);
    } else if (i < 32768 + 524288) {
        int j = i - 32768;
        int n = j >> 9, k = j & 511;
        w1t[j] = f2bf(W1[k * H2 + n]);
    } else if (i < 32768 + 2 * 524288) {
        int j = i - (32768 + 524288);
        int n = j >> 10, k = j & 1023;
        w2t[j] = f2bf(W2[k * HD + n]);
    }
}

// ---------------- histogram of dst ----------------
__global__ __launch_bounds__(256) void k_hist(const int* __restrict__ dst, int* __restrict__ counts) {
    int e = blockIdx.x * 256 + threadIdx.x;
    if (e < NE) atomicAdd(&counts[dst[e]], 1);
}

// ---------------- zero aggr rows ONLY for multi-tile (atomic) nodes ----------------
// deg<=16 nodes get plain stores in k_edge; deg==0 nodes handled in k_combine.
__global__ __launch_bounds__(256) void k_zero_heavy(const int* __restrict__ counts,
    float* __restrict__ aggr) {
    int i = blockIdx.x * 256 + threadIdx.x;
    if (i < NN && counts[i] > 16) {
        float4 z = {0.f, 0.f, 0.f, 0.f};
        float4* p = (float4*)(aggr + (size_t)i * HD);
        #pragma unroll 4
        for (int j = 0; j < HD / 4; ++j) p[j] = z;
    }
}

// ---------------- 3-phase scan of padded tile counts ----------------
__global__ __launch_bounds__(512) void k_scan1(const int* __restrict__ counts,
    int* __restrict__ tile_excl, int* __restrict__ bsum) {
    __shared__ int wsums[8];
    int b = blockIdx.x, t = threadIdx.x;
    int i = b * 512 + t;
    int v = (i < NN) ? ((counts[i] + 15) >> 4) : 0;   // tile count for node
    int lane = t & 63, wid = t >> 6;
    int x = v;
    #pragma unroll
    for (int o = 1; o < 64; o <<= 1) {
        int y = __shfl_up(x, o, 64);
        if (lane >= o) x += y;
    }
    if (lane == 63) wsums[wid] = x;
    __syncthreads();
    if (t == 0) {
        int run = 0;
        for (int w = 0; w < 8; ++w) { int tmp = wsums[w]; wsums[w] = run; run += tmp; }
    }
    __syncthreads();
    int excl = x - v + wsums[wid];
    if (i < NN) tile_excl[i] = excl;
    if (t == 511) bsum[b] = excl + v;
}

__global__ void k_scan2(const int* __restrict__ bsum, int* __restrict__ boff, int* __restrict__ Tout) {
    if (threadIdx.x == 0) {
        int run = 0;
        for (int b = 0; b < NBLK_SCAN; ++b) { boff[b] = run; run += bsum[b]; }
        Tout[0] = run;
    }
}

__global__ __launch_bounds__(512) void k_scan3(const int* __restrict__ counts,
    const int* __restrict__ tile_excl, const int* __restrict__ boff,
    int* __restrict__ cursor, int* __restrict__ node_of_tile) {
    int b = blockIdx.x, t = threadIdx.x;
    int i = b * 512 + t;
    if (i >= NN) return;
    int tc = (counts[i] + 15) >> 4;
    int ts = tile_excl[i] + boff[b];
    cursor[i] = ts * 16;
    unsigned tag = (unsigned)i | (tc > 1 ? 0x80000000u : 0u);
    for (int k = 0; k < tc; ++k) node_of_tile[ts + k] = (int)tag;
}

// ---------------- scatter edges into padded (ELL) slots ----------------
__global__ __launch_bounds__(256) void k_scatter(const int* __restrict__ src, const int* __restrict__ dst,
    int* __restrict__ cursor, int* __restrict__ srcp, int* __restrict__ eidxp) {
    int e = blockIdx.x * 256 + threadIdx.x;
    if (e < NE) {
        int d = dst[e];
        int p = atomicAdd(&cursor[d], 1);
        srcp[p] = src[e];
        eidxp[p] = e;
    }
}

// ---------------- fused edge GEMM + node-aligned reduce, NO atomics for deg<=16 ----------------
// block = 2 tiles (32 padded edge slots) x 512 cols. 4 waves, one 128-col block each.
// B fragments come straight from global (wet is L2-resident, 64 KB total):
// no Bs LDS staging -> LDS 4.6 KB/block; acc[2][8] -> 64 AGPRs. Target 4 blocks/CU.
__global__ __launch_bounds__(256, 4) void k_edge(
    const float* __restrict__ ea, const unsigned short* __restrict__ wet,
    const float* __restrict__ x, const float* __restrict__ b_e,
    const int* __restrict__ srcp, const int* __restrict__ eidxp,
    const int* __restrict__ node_of_tile, const int* __restrict__ Tptr,
    float* __restrict__ aggr) {
    int tile0 = blockIdx.x * 2;
    int T = Tptr[0];
    if (tile0 >= T) return;
    __shared__ unsigned short As[32 * LDT];   // 4.6 KB
    int t = threadIdx.x;
    int slot0 = tile0 * 16;
    // stage A: 32 gathered ea rows -> bf16 (zeros for pad slots); 8 threads/row, 8 floats each
    {
        int r = t >> 3, qq = t & 7;
        int s = srcp[slot0 + r];
        unsigned short* lp = As + r * LDT + qq * 8;
        if (s >= 0) {
            int eix = eidxp[slot0 + r];
            const float* gp = ea + (size_t)eix * EDIM + qq * 8;
            float4 v0 = ((const float4*)gp)[0];
            float4 v1 = ((const float4*)gp)[1];
            lp[0] = f2bf(v0.x); lp[1] = f2bf(v0.y); lp[2] = f2bf(v0.z); lp[3] = f2bf(v0.w);
            lp[4] = f2bf(v1.x); lp[5] = f2bf(v1.y); lp[6] = f2bf(v1.z); lp[7] = f2bf(v1.w);
        } else {
            uint4 z = {0u, 0u, 0u, 0u};
            *(uint4*)lp = z;
        }
    }
    __syncthreads();
    int wave = t >> 6, lane = t & 63, l15 = lane & 15, quad = lane >> 4;
    int cblk = wave * 128;
    f32x4 acc[2][8];
    #pragma unroll
    for (int i = 0; i < 2; ++i)
        #pragma unroll
        for (int j = 0; j < 8; ++j) acc[i][j] = (f32x4){0.f, 0.f, 0.f, 0.f};
    #pragma unroll
    for (int k0 = 0; k0 < 64; k0 += 32) {
        s16x8 af[2], bfr[8];
        #pragma unroll
        for (int i = 0; i < 2; ++i)
            af[i] = *(const s16x8*)(As + (i * 16 + l15) * LDT + k0 + quad * 8);
        #pragma unroll
        for (int j = 0; j < 8; ++j)
            bfr[j] = *(const s16x8*)(wet + (size_t)(cblk + j * 16 + l15) * EDIM + k0 + quad * 8);
        #pragma unroll
        for (int i = 0; i < 2; ++i)
            #pragma unroll
            for (int j = 0; j < 8; ++j)
                acc[i][j] = __builtin_amdgcn_mfma_f32_16x16x32_bf16(af[i], bfr[j], acc[i][j], 0, 0, 0);
    }
    float bev[8];
    #pragma unroll
    for (int j = 0; j < 8; ++j) bev[j] = b_e[cblk + j * 16 + l15];
    #pragma unroll
    for (int i = 0; i < 2; ++i) {
        int tile = tile0 + i;
        if (tile >= T) continue;
        unsigned meta = (unsigned)node_of_tile[tile];
        int v = (int)(meta & 0x7fffffffu);
        int srow = slot0 + i * 16 + quad * 4;
        float sum8[8];
        #pragma unroll
        for (int j = 0; j < 8; ++j) sum8[j] = 0.f;
        #pragma unroll
        for (int r = 0; r < 4; ++r) {
            int s = srcp[srow + r];
            if (s >= 0) {
                const float* xr = x + (size_t)s * HD + cblk;
                #pragma unroll
                for (int j = 0; j < 8; ++j) {
                    float vv = acc[i][j][r] + xr[j * 16 + l15] + bev[j];
                    sum8[j] += vv > 0.f ? vv : 0.f;
                }
            }
        }
        #pragma unroll
        for (int j = 0; j < 8; ++j) {
            sum8[j] += __shfl_xor(sum8[j], 16, 64);
            sum8[j] += __shfl_xor(sum8[j], 32, 64);
        }
        if (quad == 0) {
            float* ap = aggr + (size_t)v * HD + cblk;
            if (meta & 0x80000000u) {
                #pragma unroll
                for (int j = 0; j < 8; ++j) atomicAdd(ap + j * 16 + l15, sum8[j]);
            } else {
                #pragma unroll
                for (int j = 0; j < 8; ++j) ap[j * 16 + l15] = sum8[j];
            }
        }
    }
}

// ---------------- h = bf16((1+eps)*x + aggr), aggr treated as 0 for deg-0 nodes ----------------
__global__ __launch_bounds__(256) void k_combine(const float* __restrict__ aggr,
    const float* __restrict__ x, const int* __restrict__ counts,
    const float* __restrict__ eps, unsigned short* __restrict__ h) {
    long i = ((long)blockIdx.x * 256 + threadIdx.x) * 4;
    if (i >= (long)NN * HD) return;
    float ep = 1.0f + eps[0];
    int v = (int)(i >> 9);   // 512 floats per row
    float4 xv = *(const float4*)(x + i);
    float4 a = {0.f, 0.f, 0.f, 0.f};
    if (counts[v] != 0) a = *(const float4*)(aggr + i);
    uint2 p;
    p.x = (unsigned)f2bf(ep * xv.x + a.x) | ((unsigned)f2bf(ep * xv.y + a.y) << 16);
    p.y = (unsigned)f2bf(ep * xv.z + a.z) | ((unsigned)f2bf(ep * xv.w + a.w) << 16);
    *(uint2*)(h + i) = p;
}

// ---------------- bf16 GEMM + bias + BN column stats; optional fused SiLU-BN on A ----------------
template <bool BF16OUT, bool SILU_A>
__global__ __launch_bounds__(256) void k_gemm_bn(
    const unsigned short* __restrict__ A, const unsigned short* __restrict__ Bt,
    const float* __restrict__ bias, void* __restrict__ Cv,
    float* __restrict__ bn_sum, float* __restrict__ bn_sumsq,
    const float* __restrict__ a_sc, const float* __restrict__ a_sb,
    int M, int K, int Nn) {
    __shared__ unsigned short As[128 * LDT];
    __shared__ unsigned short Bs[128 * LDT];
    __shared__ float csum[128], csumsq[128];
    int mblk = blockIdx.x, nblk = blockIdx.y;
    int t = threadIdx.x;
    int row0 = mblk * 128, col0 = nblk * 128;
    int wid = t >> 6, lane = t & 63, l15 = lane & 15, quad = lane >> 4;
    f32x4 acc[2][8];
    #pragma unroll
    for (int i = 0; i < 2; ++i)
        #pragma unroll
        for (int j = 0; j < 8; ++j) acc[i][j] = (f32x4){0.f, 0.f, 0.f, 0.f};

    for (int k0 = 0; k0 < K; k0 += 64) {
        __syncthreads();
        {
            int r = t >> 1, half = t & 1;
            int row = row0 + r;
            int kb = k0 + half * 32;
            unsigned short* lp = As + r * LDT + half * 32;
            if (row < M) {
                const unsigned short* gp = A + (size_t)row * K + kb;
                if (SILU_A) {
                    #pragma unroll
                    for (int jj = 0; jj < 4; ++jj) {
                        uint4 u = *(const uint4*)(gp + jj * 8);
                        float4 sA = *(const float4*)(a_sc + kb + jj * 8);
                        float4 sB = *(const float4*)(a_sc + kb + jj * 8 + 4);
                        float4 bA = *(const float4*)(a_sb + kb + jj * 8);
                        float4 bB = *(const float4*)(a_sb + kb + jj * 8 + 4);
                        unsigned short o[8];
                        o[0] = f2bf(silu_f(bf2f((unsigned short)(u.x & 0xffffu)) * sA.x + bA.x));
                        o[1] = f2bf(silu_f(bf2f((unsigned short)(u.x >> 16)) * sA.y + bA.y));
                        o[2] = f2bf(silu_f(bf2f((unsigned short)(u.y & 0xffffu)) * sA.z + bA.z));
                        o[3] = f2bf(silu_f(bf2f((unsigned short)(u.y >> 16)) * sA.w + bA.w));
                        o[4] = f2bf(silu_f(bf2f((unsigned short)(u.z & 0xffffu)) * sB.x + bB.x));
                        o[5] = f2bf(silu_f(bf2f((unsigned short)(u.z >> 16)) * sB.y + bB.y));
                        o[6] = f2bf(silu_f(bf2f((unsigned short)(u.w & 0xffffu)) * sB.z + bB.z));
                        o[7] = f2bf(silu_f(bf2f((unsigned short)(u.w >> 16)) * sB.w + bB.w));
                        #pragma unroll
                        for (int m = 0; m < 8; ++m) lp[jj * 8 + m] = o[m];
                    }
                } else {
                    #pragma unroll
                    for (int jj = 0; jj < 4; ++jj) *(uint4*)(lp + jj * 8) = *(const uint4*)(gp + jj * 8);
                }
            } else {
                uint4 z = {0u, 0u, 0u, 0u};
                #pragma unroll
                for (int jj = 0; jj < 4; ++jj) *(uint4*)(lp + jj * 8) = z;
            }
            const unsigned short* gb = Bt + (size_t)(col0 + r) * K + kb;
            unsigned short* lb = Bs + r * LDT + half * 32;
            #pragma unroll
            for (int jj = 0; jj < 4; ++jj) *(uint4*)(lb + jj * 8) = *(const uint4*)(gb + jj * 8);
        }
        __syncthreads();
        #pragma unroll
        for (int kk = 0; kk < 64; kk += 32) {
            s16x8 af[2], bfr[8];
            #pragma unroll
            for (int i = 0; i < 2; ++i)
                af[i] = *(const s16x8*)(As + (wid * 32 + i * 16 + l15) * LDT + kk + quad * 8);
            #pragma unroll
            for (int j = 0; j < 8; ++j)
                bfr[j] = *(const s16x8*)(Bs + (j * 16 + l15) * LDT + kk + quad * 8);
            #pragma unroll
            for (int i = 0; i < 2; ++i)
                #pragma unroll
                for (int j = 0; j < 8; ++j)
                    acc[i][j] = __builtin_amdgcn_mfma_f32_16x16x32_bf16(af[i], bfr[j], acc[i][j], 0, 0, 0);
        }
    }
    if (t < 128) { csum[t] = 0.f; csumsq[t] = 0.f; }
    __syncthreads();
    int mrow0 = row0 + wid * 32;
    #pragma unroll
    for (int j = 0; j < 8; ++j) {
        int col = j * 16 + l15;
        float bv = bias[col0 + col];
        float ls = 0.f, lq = 0.f;
        #pragma unroll
        for (int i = 0; i < 2; ++i) {
            #pragma unroll
            for (int r = 0; r < 4; ++r) {
                int row = mrow0 + i * 16 + quad * 4 + r;
                if (row < M) {
                    float v = acc[i][j][r] + bv;
                    if (BF16OUT)
                        ((unsigned short*)Cv)[(size_t)row * Nn + col0 + col] = f2bf(v);
                    else
                        ((float*)Cv)[(size_t)row * Nn + col0 + col] = v;
                    ls += v; lq += v * v;
                }
            }
        }
        atomicAdd(&csum[col], ls);
        atomicAdd(&csumsq[col], lq);
    }
    __syncthreads();
    if (t < 128) {
        atomicAdd(bn_sum + col0 + t, csum[t]);
        atomicAdd(bn_sumsq + col0 + t, csumsq[t]);
    }
}

// ---------------- BN finalize ----------------
__global__ __launch_bounds__(256) void k_bn_final(const float* __restrict__ s,
    const float* __restrict__ q, const float* __restrict__ g, const float* __restrict__ beta,
    float* __restrict__ scale, float* __restrict__ sbias, int C, float invN) {
    int c = blockIdx.x * 256 + threadIdx.x;
    if (c < C) {
        float mu = s[c] * invN;
        float var = q[c] * invN - mu * mu;
        var = fmaxf(var, 0.f);
        float sc = g[c] * rsqrtf(var + 1e-5f);
        scale[c] = sc;
        sbias[c] = beta[c] - mu * sc;
    }
}

// ---------------- in-place out = silu(out*scale+bias) fp32 ----------------
__global__ __launch_bounds__(256) void k_out(float* __restrict__ out,
    const float* __restrict__ sc, const float* __restrict__ sb, long total) {
    long i = ((long)blockIdx.x * 256 + threadIdx.x) * 4;
    if (i >= total) return;
    int c = (int)(i & (HD - 1));
    float4 v = *(const float4*)(out + i);
    float4 s4 = *(const float4*)(sc + c);
    float4 b4 = *(const float4*)(sb + c);
    float4 o;
    o.x = silu_f(v.x * s4.x + b4.x);
    o.y = silu_f(v.y * s4.y + b4.y);
    o.z = silu_f(v.z * s4.z + b4.z);
    o.w = silu_f(v.w * s4.w + b4.w);
    *(float4*)(out + i) = o;
}

extern "C" void kernel_launch(void* const* d_in, const int* in_sizes, int n_in,
                              void* d_out, int out_size, void* d_ws, size_t ws_size,
                              hipStream_t stream) {
    const float* x      = (const float*)d_in[0];
    const float* ea     = (const float*)d_in[1];
    const int*   ei     = (const int*)d_in[2];     // [2][E]: src then dst
    const float* W_e    = (const float*)d_in[3];
    const float* b_e    = (const float*)d_in[4];
    const float* W1     = (const float*)d_in[5];
    const float* b1     = (const float*)d_in[6];
    const float* g1     = (const float*)d_in[7];
    const float* beta1  = (const float*)d_in[8];
    const float* W2     = (const float*)d_in[9];
    const float* b2     = (const float*)d_in[10];
    const float* g2     = (const float*)d_in[11];
    const float* beta2  = (const float*)d_in[12];
    const float* eps    = (const float*)d_in[13];
    float* out = (float*)d_out;
    char* ws = (char*)d_ws;

    float*          aggr = (float*)(ws + OFF_AGGR);
    unsigned short* h1   = (unsigned short*)(ws + OFF_H1);   // aliases aggr (dead then)
    unsigned short* h    = (unsigned short*)(ws + OFF_H);
    unsigned short* wet  = (unsigned short*)(ws + OFF_WET);
    unsigned short* w1t  = (unsigned short*)(ws + OFF_W1T);
    unsigned short* w2t  = (unsigned short*)(ws + OFF_W2T);
    int* counts  = (int*)(ws + OFF_CNT);
    float* b1s   = (float*)(ws + OFF_B1S);
    float* b1q   = (float*)(ws + OFF_B1Q);
    float* b2s   = (float*)(ws + OFF_B2S);
    float* b2q   = (float*)(ws + OFF_B2Q);
    int* tex     = (int*)(ws + OFF_TEX);
    int* bsum    = (int*)(ws + OFF_BSUM);
    int* boff    = (int*)(ws + OFF_BOFF);
    int* Tptr    = (int*)(ws + OFF_T);
    int* cursor  = (int*)(ws + OFF_CUR);
    int* notile  = (int*)(ws + OFF_NOT);
    int* srcp    = (int*)(ws + OFF_SRCP);
    int* eidxp   = (int*)(ws + OFF_EIXP);
    float* sc1   = (float*)(ws + OFF_SC1);
    float* sb1   = (float*)(ws + OFF_SB1);
    float* sc2   = (float*)(ws + OFF_SC2);
    float* sb2   = (float*)(ws + OFF_SB2);

    hipMemsetAsync(ws + OFF_CNT, 0, ZERO_BYTES, stream);
    hipMemsetAsync(srcp, 0xFF, (size_t)CAP_SLOT * 4, stream);
    k_convert<<<4224, 256, 0, stream>>>(W_e, W1, W2, wet, w1t, w2t);
    k_hist<<<(NE + 255) / 256, 256, 0, stream>>>(ei + NE, counts);
    k_zero_heavy<<<(NN + 255) / 256, 256, 0, stream>>>(counts, aggr);
    k_scan1<<<NBLK_SCAN, 512, 0, stream>>>(counts, tex, bsum);
    k_scan2<<<1, 64, 0, stream>>>(bsum, boff, Tptr);
    k_scan3<<<NBLK_SCAN, 512, 0, stream>>>(counts, tex, boff, cursor, notile);
    k_scatter<<<(NE + 255) / 256, 256, 0, stream>>>(ei, ei + NE, cursor, srcp, eidxp);
    k_edge<<<CAP_TILE / 2, 256, 0, stream>>>(ea, wet, x, b_e, srcp, eidxp, notile, Tptr, aggr);
    k_combine<<<(int)(((long)NN * HD / 4 + 255) / 256), 256, 0, stream>>>(aggr, x, counts, eps, h);
    k_gemm_bn<true, false><<<dim3((NN + 127) / 128, H2 / 128), 256, 0, stream>>>(
        h, w1t, b1, h1, b1s, b1q, nullptr, nullptr, NN, HD, H2);
    k_bn_final<<<4, 256, 0, stream>>>(b1s, b1q, g1, beta1, sc1, sb1, H2, 1.f / NN);
    k_gemm_bn<false, true><<<dim3((NN + 127) / 128, HD / 128), 256, 0, stream>>>(
        h1, w2t, b2, out, b2s, b2q, sc1, sb1, NN, H2, HD);
    k_bn_final<<<2, 256, 0, stream>>>(b2s, b2q, g2, beta2, sc2, sb2, HD, 1.f / NN);
    k_out<<<(int)(((long)NN * HD / 4 + 255) / 256), 256, 0, stream>>>(out, sc2, sb2, (long)NN * HD);
}

// Round 2
// 1080.722 us; speedup vs baseline: 1.0787x; 1.0358x over previous
//
#include <hip/hip_runtime.h>
#include <math.h>

#define NN 50000
#define NE 400000
#define HD 512
#define EDIM 64
#define H2 1024
#define LDT 72           // padded LDS row stride (ushorts)
#define CAP_SLOT 1200000 // padded edge-slot capacity (>= NE + 16*NN worst pad)
#define CAP_TILE 75000   // CAP_SLOT/16
#define NBLK_SCAN 98     // ceil(NN/512)

typedef short s16x8 __attribute__((ext_vector_type(8)));
typedef float f32x4 __attribute__((ext_vector_type(4)));

__device__ __forceinline__ unsigned short f2bf(float f) {
    union { float f; unsigned u; } v; v.f = f;
    unsigned r = v.u + 0x7fffu + ((v.u >> 16) & 1u);
    return (unsigned short)(r >> 16);
}
__device__ __forceinline__ float bf2f(unsigned short h) {
    union { unsigned u; float f; } v; v.u = ((unsigned)h) << 16;
    return v.f;
}
__device__ __forceinline__ float silu_f(float t) {
    return t / (1.f + __expf(-t));
}

// ---------------- workspace layout (bytes), total ~166.3 MB ----------------
constexpr size_t OFF_AGGR = 0;                        // f32 [NN][512]; DEAD after k_combine
constexpr size_t OFF_H1   = 0;                        // bf16 [NN][1024] (aliases aggr)
constexpr size_t OFF_H    = 102400000;                // bf16 [NN][512]
constexpr size_t OFF_WET  = 153600000;                // bf16 [512][64]
constexpr size_t OFF_W1T  = OFF_WET + 65536;          // bf16 [1024][512]
constexpr size_t OFF_W2T  = OFF_W1T + 1048576;        // bf16 [512][1024]
constexpr size_t OFF_CNT  = OFF_W2T + 1048576;        // int[50000]   (zeroed)
constexpr size_t OFF_B1S  = OFF_CNT + 200000;         // float[1024]  (zeroed)
constexpr size_t OFF_B1Q  = OFF_B1S + 4096;           // float[1024]  (zeroed)
constexpr size_t OFF_B2S  = OFF_B1Q + 4096;           // float[512]   (zeroed)
constexpr size_t OFF_B2Q  = OFF_B2S + 2048;           // float[512]   (zeroed)
constexpr size_t ZERO_BYTES = 200000 + 4096 + 4096 + 2048 + 2048;
constexpr size_t OFF_TEX  = OFF_B2Q + 2048;           // int[50000] tile_excl
constexpr size_t OFF_BSUM = OFF_TEX + 200000;         // int[128]
constexpr size_t OFF_BOFF = OFF_BSUM + 512;           // int[128]
constexpr size_t OFF_T    = OFF_BOFF + 512;           // int[16]
constexpr size_t OFF_CUR  = OFF_T + 64;               // int[50000]
constexpr size_t OFF_NOT  = OFF_CUR + 200000;         // int[75008] node_of_tile
constexpr size_t OFF_SRCP = OFF_NOT + 300032;         // int[CAP_SLOT] (memset 0xFF)
constexpr size_t OFF_EIXP = OFF_SRCP + 4800000;       // int[CAP_SLOT]
constexpr size_t OFF_SC1  = OFF_EIXP + 4800000;       // float[1024]
constexpr size_t OFF_SB1  = OFF_SC1 + 4096;           // float[1024]
constexpr size_t OFF_SC2  = OFF_SB1 + 4096;           // float[512]
constexpr size_t OFF_SB2  = OFF_SC2 + 2048;           // float[512]

// ---------------- weight transpose+convert to bf16 ----------------
__global__ __launch_bounds__(256) void k_convert(const float* __restrict__ We,
    const float* __restrict__ W1, const float* __restrict__ W2,
    unsigned short* __restrict__ wet, unsigned short* __restrict__ w1t,
    unsigned short* __restrict__ w2t) {
    int i = blockIdx.x * 256 + threadIdx.x;
    if (i < 32768) {
        int n = i >> 6, k = i & 63;
        wet[i] = f2bf(We[k * HD + n]);
    } else if (i < 32768 + 524288) {
        int j = i - 32768;
        int n = j >> 9, k = j & 511;
        w1t[j] = f2bf(W1[k * H2 + n]);
    } else if (i < 32768 + 2 * 524288) {
        int j = i - (32768 + 524288);
        int n = j >> 10, k = j & 1023;
        w2t[j] = f2bf(W2[k * HD + n]);
    }
}

// ---------------- histogram of dst ----------------
__global__ __launch_bounds__(256) void k_hist(const int* __restrict__ dst, int* __restrict__ counts) {
    int e = blockIdx.x * 256 + threadIdx.x;
    if (e < NE) atomicAdd(&counts[dst[e]], 1);
}

// ---------------- zero aggr rows ONLY for multi-tile (atomic) nodes ----------------
__global__ __launch_bounds__(256) void k_zero_heavy(const int* __restrict__ counts,
    float* __restrict__ aggr) {
    int i = blockIdx.x * 256 + threadIdx.x;
    if (i < NN && counts[i] > 16) {
        float4 z = {0.f, 0.f, 0.f, 0.f};
        float4* p = (float4*)(aggr + (size_t)i * HD);
        #pragma unroll 4
        for (int j = 0; j < HD / 4; ++j) p[j] = z;
    }
}

// ---------------- 3-phase scan of padded tile counts ----------------
__global__ __launch_bounds__(512) void k_scan1(const int* __restrict__ counts,
    int* __restrict__ tile_excl, int* __restrict__ bsum) {
    __shared__ int wsums[8];
    int b = blockIdx.x, t = threadIdx.x;
    int i = b * 512 + t;
    int v = (i < NN) ? ((counts[i] + 15) >> 4) : 0;   // tile count for node
    int lane = t & 63, wid = t >> 6;
    int x = v;
    #pragma unroll
    for (int o = 1; o < 64; o <<= 1) {
        int y = __shfl_up(x, o, 64);
        if (lane >= o) x += y;
    }
    if (lane == 63) wsums[wid] = x;
    __syncthreads();
    if (t == 0) {
        int run = 0;
        for (int w = 0; w < 8; ++w) { int tmp = wsums[w]; wsums[w] = run; run += tmp; }
    }
    __syncthreads();
    int excl = x - v + wsums[wid];
    if (i < NN) tile_excl[i] = excl;
    if (t == 511) bsum[b] = excl + v;
}

__global__ void k_scan2(const int* __restrict__ bsum, int* __restrict__ boff, int* __restrict__ Tout) {
    if (threadIdx.x == 0) {
        int run = 0;
        for (int b = 0; b < NBLK_SCAN; ++b) { boff[b] = run; run += bsum[b]; }
        Tout[0] = run;
    }
}

__global__ __launch_bounds__(512) void k_scan3(const int* __restrict__ counts,
    const int* __restrict__ tile_excl, const int* __restrict__ boff,
    int* __restrict__ cursor, int* __restrict__ node_of_tile) {
    int b = blockIdx.x, t = threadIdx.x;
    int i = b * 512 + t;
    if (i >= NN) return;
    int tc = (counts[i] + 15) >> 4;
    int ts = tile_excl[i] + boff[b];
    cursor[i] = ts * 16;
    unsigned tag = (unsigned)i | (tc > 1 ? 0x80000000u : 0u);
    for (int k = 0; k < tc; ++k) node_of_tile[ts + k] = (int)tag;
}

// ---------------- scatter edges into padded (ELL) slots ----------------
__global__ __launch_bounds__(256) void k_scatter(const int* __restrict__ src, const int* __restrict__ dst,
    int* __restrict__ cursor, int* __restrict__ srcp, int* __restrict__ eidxp) {
    int e = blockIdx.x * 256 + threadIdx.x;
    if (e < NE) {
        int d = dst[e];
        int p = atomicAdd(&cursor[d], 1);
        srcp[p] = src[e];
        eidxp[p] = e;
    }
}

// ---------------- fused edge GEMM + node-aligned reduce, NO atomics for deg<=16 ----------------
// block = 2 tiles (32 padded edge slots) x 512 cols. 4 waves, one 128-col block each.
// Epilogue x-gather is branch-free (clamped addr + mask-fma) so loads pipeline;
// non-atomic stores repacked via per-wave LDS slot into 512B contiguous float4 lines.
__global__ __launch_bounds__(256, 4) void k_edge(
    const float* __restrict__ ea, const unsigned short* __restrict__ wet,
    const float* __restrict__ x, const float* __restrict__ b_e,
    const int* __restrict__ srcp, const int* __restrict__ eidxp,
    const int* __restrict__ node_of_tile, const int* __restrict__ Tptr,
    float* __restrict__ aggr) {
    int tile0 = blockIdx.x * 2;
    int T = Tptr[0];
    if (tile0 >= T) return;
    __shared__ unsigned short As[32 * LDT];   // 4.6 KB
    __shared__ int Ss[32];                    // srcp cache
    __shared__ float Rs[4][128];              // per-wave store repack, 2 KB
    int t = threadIdx.x;
    int slot0 = tile0 * 16;
    // stage A: 32 gathered ea rows -> bf16 (zeros for pad slots); 8 threads/row
    {
        int r = t >> 3, qq = t & 7;
        int s = srcp[slot0 + r];
        if (qq == 0) Ss[r] = s;
        unsigned short* lp = As + r * LDT + qq * 8;
        if (s >= 0) {
            int eix = eidxp[slot0 + r];
            const float* gp = ea + (size_t)eix * EDIM + qq * 8;
            float4 v0 = ((const float4*)gp)[0];
            float4 v1 = ((const float4*)gp)[1];
            lp[0] = f2bf(v0.x); lp[1] = f2bf(v0.y); lp[2] = f2bf(v0.z); lp[3] = f2bf(v0.w);
            lp[4] = f2bf(v1.x); lp[5] = f2bf(v1.y); lp[6] = f2bf(v1.z); lp[7] = f2bf(v1.w);
        } else {
            uint4 z = {0u, 0u, 0u, 0u};
            *(uint4*)lp = z;
        }
    }
    __syncthreads();
    int wave = t >> 6, lane = t & 63, l15 = lane & 15, quad = lane >> 4;
    int cblk = wave * 128;
    f32x4 acc[2][8];
    #pragma unroll
    for (int i = 0; i < 2; ++i)
        #pragma unroll
        for (int j = 0; j < 8; ++j) acc[i][j] = (f32x4){0.f, 0.f, 0.f, 0.f};
    #pragma unroll
    for (int k0 = 0; k0 < 64; k0 += 32) {
        s16x8 af[2], bfr[8];
        #pragma unroll
        for (int i = 0; i < 2; ++i)
            af[i] = *(const s16x8*)(As + (i * 16 + l15) * LDT + k0 + quad * 8);
        #pragma unroll
        for (int j = 0; j < 8; ++j)
            bfr[j] = *(const s16x8*)(wet + (size_t)(cblk + j * 16 + l15) * EDIM + k0 + quad * 8);
        #pragma unroll
        for (int i = 0; i < 2; ++i)
            #pragma unroll
            for (int j = 0; j < 8; ++j)
                acc[i][j] = __builtin_amdgcn_mfma_f32_16x16x32_bf16(af[i], bfr[j], acc[i][j], 0, 0, 0);
    }
    float bev[8];
    #pragma unroll
    for (int j = 0; j < 8; ++j) bev[j] = b_e[cblk + j * 16 + l15];
    float* rp = Rs[wave];
    #pragma unroll
    for (int i = 0; i < 2; ++i) {
        int tile = tile0 + i;
        unsigned meta = (unsigned)node_of_tile[tile];   // in-bounds (buffer padded), garbage ok if tile>=T
        int srow = i * 16 + quad * 4;
        float sum8[8];
        #pragma unroll
        for (int j = 0; j < 8; ++j) sum8[j] = 0.f;
        // branch-free gather in 2-row groups: 16 independent dword loads in flight
        #pragma unroll
        for (int r2 = 0; r2 < 2; ++r2) {
            float xv[2][8], msk[2];
            const float* xp[2];
            #pragma unroll
            for (int r = 0; r < 2; ++r) {
                int s = Ss[srow + r2 * 2 + r];
                msk[r] = s >= 0 ? 1.f : 0.f;
                xp[r] = x + (size_t)(s >= 0 ? s : 0) * HD + cblk + l15;
            }
            #pragma unroll
            for (int r = 0; r < 2; ++r)
                #pragma unroll
                for (int j = 0; j < 8; ++j) xv[r][j] = xp[r][j * 16];
            #pragma unroll
            for (int r = 0; r < 2; ++r) {
                int rr = r2 * 2 + r;
                #pragma unroll
                for (int j = 0; j < 8; ++j) {
                    float vv = acc[i][j][rr] + xv[r][j] + bev[j];
                    vv = vv > 0.f ? vv : 0.f;
                    sum8[j] = fmaf(msk[r], vv, sum8[j]);
                }
            }
        }
        #pragma unroll
        for (int j = 0; j < 8; ++j) {
            sum8[j] += __shfl_xor(sum8[j], 16, 64);
            sum8[j] += __shfl_xor(sum8[j], 32, 64);
        }
        if (tile < T) {
            int v = (int)(meta & 0x7fffffffu);
            float* ap = aggr + (size_t)v * HD + cblk;
            if (meta & 0x80000000u) {
                if (quad == 0) {
                    #pragma unroll
                    for (int j = 0; j < 8; ++j) atomicAdd(ap + j * 16 + l15, sum8[j]);
                }
            } else {
                // all 64 lanes hold the full sums after xor-reduce; repack to contiguous
                rp[(quad * 2 + 0) * 16 + l15] = sum8[quad * 2 + 0];
                rp[(quad * 2 + 1) * 16 + l15] = sum8[quad * 2 + 1];
                // same-wave LDS ops complete in order; no barrier needed
                if (lane < 32) {
                    float4 vv4 = *(const float4*)(rp + lane * 4);
                    *(float4*)(ap + lane * 4) = vv4;
                }
            }
        }
    }
}

// ---------------- h = bf16((1+eps)*x + aggr), aggr treated as 0 for deg-0 nodes ----------------
__global__ __launch_bounds__(256) void k_combine(const float* __restrict__ aggr,
    const float* __restrict__ x, const int* __restrict__ counts,
    const float* __restrict__ eps, unsigned short* __restrict__ h) {
    long i = ((long)blockIdx.x * 256 + threadIdx.x) * 4;
    if (i >= (long)NN * HD) return;
    float ep = 1.0f + eps[0];
    int v = (int)(i >> 9);   // 512 floats per row
    float4 xv = *(const float4*)(x + i);
    float4 a = {0.f, 0.f, 0.f, 0.f};
    if (counts[v] != 0) a = *(const float4*)(aggr + i);
    uint2 p;
    p.x = (unsigned)f2bf(ep * xv.x + a.x) | ((unsigned)f2bf(ep * xv.y + a.y) << 16);
    p.y = (unsigned)f2bf(ep * xv.z + a.z) | ((unsigned)f2bf(ep * xv.w + a.w) << 16);
    *(uint2*)(h + i) = p;
}

// ---------------- bf16 GEMM + bias + BN column stats; optional fused SiLU-BN on A ----------------
template <bool BF16OUT, bool SILU_A>
__global__ __launch_bounds__(256) void k_gemm_bn(
    const unsigned short* __restrict__ A, const unsigned short* __restrict__ Bt,
    const float* __restrict__ bias, void* __restrict__ Cv,
    float* __restrict__ bn_sum, float* __restrict__ bn_sumsq,
    const float* __restrict__ a_sc, const float* __restrict__ a_sb,
    int M, int K, int Nn) {
    __shared__ unsigned short As[128 * LDT];
    __shared__ unsigned short Bs[128 * LDT];
    __shared__ float csum[128], csumsq[128];
    int mblk = blockIdx.x, nblk = blockIdx.y;
    int t = threadIdx.x;
    int row0 = mblk * 128, col0 = nblk * 128;
    int wid = t >> 6, lane = t & 63, l15 = lane & 15, quad = lane >> 4;
    f32x4 acc[2][8];
    #pragma unroll
    for (int i = 0; i < 2; ++i)
        #pragma unroll
        for (int j = 0; j < 8; ++j) acc[i][j] = (f32x4){0.f, 0.f, 0.f, 0.f};

    for (int k0 = 0; k0 < K; k0 += 64) {
        __syncthreads();
        {
            int r = t >> 1, half = t & 1;
            int row = row0 + r;
            int kb = k0 + half * 32;
            unsigned short* lp = As + r * LDT + half * 32;
            if (row < M) {
                const unsigned short* gp = A + (size_t)row * K + kb;
                if (SILU_A) {
                    #pragma unroll
                    for (int jj = 0; jj < 4; ++jj) {
                        uint4 u = *(const uint4*)(gp + jj * 8);
                        float4 sA = *(const float4*)(a_sc + kb + jj * 8);
                        float4 sB = *(const float4*)(a_sc + kb + jj * 8 + 4);
                        float4 bA = *(const float4*)(a_sb + kb + jj * 8);
                        float4 bB = *(const float4*)(a_sb + kb + jj * 8 + 4);
                        unsigned short o[8];
                        o[0] = f2bf(silu_f(bf2f((unsigned short)(u.x & 0xffffu)) * sA.x + bA.x));
                        o[1] = f2bf(silu_f(bf2f((unsigned short)(u.x >> 16)) * sA.y + bA.y));
                        o[2] = f2bf(silu_f(bf2f((unsigned short)(u.y & 0xffffu)) * sA.z + bA.z));
                        o[3] = f2bf(silu_f(bf2f((unsigned short)(u.y >> 16)) * sA.w + bA.w));
                        o[4] = f2bf(silu_f(bf2f((unsigned short)(u.z & 0xffffu)) * sB.x + bB.x));
                        o[5] = f2bf(silu_f(bf2f((unsigned short)(u.z >> 16)) * sB.y + bB.y));
                        o[6] = f2bf(silu_f(bf2f((unsigned short)(u.w & 0xffffu)) * sB.z + bB.z));
                        o[7] = f2bf(silu_f(bf2f((unsigned short)(u.w >> 16)) * sB.w + bB.w));
                        #pragma unroll
                        for (int m = 0; m < 8; ++m) lp[jj * 8 + m] = o[m];
                    }
                } else {
                    #pragma unroll
                    for (int jj = 0; jj < 4; ++jj) *(uint4*)(lp + jj * 8) = *(const uint4*)(gp + jj * 8);
                }
            } else {
                uint4 z = {0u, 0u, 0u, 0u};
                #pragma unroll
                for (int jj = 0; jj < 4; ++jj) *(uint4*)(lp + jj * 8) = z;
            }
            const unsigned short* gb = Bt + (size_t)(col0 + r) * K + kb;
            unsigned short* lb = Bs + r * LDT + half * 32;
            #pragma unroll
            for (int jj = 0; jj < 4; ++jj) *(uint4*)(lb + jj * 8) = *(const uint4*)(gb + jj * 8);
        }
        __syncthreads();
        #pragma unroll
        for (int kk = 0; kk < 64; kk += 32) {
            s16x8 af[2], bfr[8];
            #pragma unroll
            for (int i = 0; i < 2; ++i)
                af[i] = *(const s16x8*)(As + (wid * 32 + i * 16 + l15) * LDT + kk + quad * 8);
            #pragma unroll
            for (int j = 0; j < 8; ++j)
                bfr[j] = *(const s16x8*)(Bs + (j * 16 + l15) * LDT + kk + quad * 8);
            #pragma unroll
            for (int i = 0; i < 2; ++i)
                #pragma unroll
                for (int j = 0; j < 8; ++j)
                    acc[i][j] = __builtin_amdgcn_mfma_f32_16x16x32_bf16(af[i], bfr[j], acc[i][j], 0, 0, 0);
        }
    }
    if (t < 128) { csum[t] = 0.f; csumsq[t] = 0.f; }
    __syncthreads();
    int mrow0 = row0 + wid * 32;
    #pragma unroll
    for (int j = 0; j < 8; ++j) {
        int col = j * 16 + l15;
        float bv = bias[col0 + col];
        float ls = 0.f, lq = 0.f;
        #pragma unroll
        for (int i = 0; i < 2; ++i) {
            #pragma unroll
            for (int r = 0; r < 4; ++r) {
                int row = mrow0 + i * 16 + quad * 4 + r;
                if (row < M) {
                    float v = acc[i][j][r] + bv;
                    if (BF16OUT)
                        ((unsigned short*)Cv)[(size_t)row * Nn + col0 + col] = f2bf(v);
                    else
                        ((float*)Cv)[(size_t)row * Nn + col0 + col] = v;
                    ls += v; lq += v * v;
                }
            }
        }
        atomicAdd(&csum[col], ls);
        atomicAdd(&csumsq[col], lq);
    }
    __syncthreads();
    if (t < 128) {
        atomicAdd(bn_sum + col0 + t, csum[t]);
        atomicAdd(bn_sumsq + col0 + t, csumsq[t]);
    }
}

// ---------------- BN finalize ----------------
__global__ __launch_bounds__(256) void k_bn_final(const float* __restrict__ s,
    const float* __restrict__ q, const float* __restrict__ g, const float* __restrict__ beta,
    float* __restrict__ scale, float* __restrict__ sbias, int C, float invN) {
    int c = blockIdx.x * 256 + threadIdx.x;
    if (c < C) {
        float mu = s[c] * invN;
        float var = q[c] * invN - mu * mu;
        var = fmaxf(var, 0.f);
        float sc = g[c] * rsqrtf(var + 1e-5f);
        scale[c] = sc;
        sbias[c] = beta[c] - mu * sc;
    }
}

// ---------------- in-place out = silu(out*scale+bias) fp32 ----------------
__global__ __launch_bounds__(256) void k_out(float* __restrict__ out,
    const float* __restrict__ sc, const float* __restrict__ sb, long total) {
    long i = ((long)blockIdx.x * 256 + threadIdx.x) * 4;
    if (i >= total) return;
    int c = (int)(i & (HD - 1));
    float4 v = *(const float4*)(out + i);
    float4 s4 = *(const float4*)(sc + c);
    float4 b4 = *(const float4*)(sb + c);
    float4 o;
    o.x = silu_f(v.x * s4.x + b4.x);
    o.y = silu_f(v.y * s4.y + b4.y);
    o.z = silu_f(v.z * s4.z + b4.z);
    o.w = silu_f(v.w * s4.w + b4.w);
    *(float4*)(out + i) = o;
}

extern "C" void kernel_launch(void* const* d_in, const int* in_sizes, int n_in,
                              void* d_out, int out_size, void* d_ws, size_t ws_size,
                              hipStream_t stream) {
    const float* x      = (const float*)d_in[0];
    const float* ea     = (const float*)d_in[1];
    const int*   ei     = (const int*)d_in[2];     // [2][E]: src then dst
    const float* W_e    = (const float*)d_in[3];
    const float* b_e    = (const float*)d_in[4];
    const float* W1     = (const float*)d_in[5];
    const float* b1     = (const float*)d_in[6];
    const float* g1     = (const float*)d_in[7];
    const float* beta1  = (const float*)d_in[8];
    const float* W2     = (const float*)d_in[9];
    const float* b2     = (const float*)d_in[10];
    const float* g2     = (const float*)d_in[11];
    const float* beta2  = (const float*)d_in[12];
    const float* eps    = (const float*)d_in[13];
    float* out = (float*)d_out;
    char* ws = (char*)d_ws;

    float*          aggr = (float*)(ws + OFF_AGGR);
    unsigned short* h1   = (unsigned short*)(ws + OFF_H1);   // aliases aggr (dead then)
    unsigned short* h    = (unsigned short*)(ws + OFF_H);
    unsigned short* wet  = (unsigned short*)(ws + OFF_WET);
    unsigned short* w1t  = (unsigned short*)(ws + OFF_W1T);
    unsigned short* w2t  = (unsigned short*)(ws + OFF_W2T);
    int* counts  = (int*)(ws + OFF_CNT);
    float* b1s   = (float*)(ws + OFF_B1S);
    float* b1q   = (float*)(ws + OFF_B1Q);
    float* b2s   = (float*)(ws + OFF_B2S);
    float* b2q   = (float*)(ws + OFF_B2Q);
    int* tex     = (int*)(ws + OFF_TEX);
    int* bsum    = (int*)(ws + OFF_BSUM);
    int* boff    = (int*)(ws + OFF_BOFF);
    int* Tptr    = (int*)(ws + OFF_T);
    int* cursor  = (int*)(ws + OFF_CUR);
    int* notile  = (int*)(ws + OFF_NOT);
    int* srcp    = (int*)(ws + OFF_SRCP);
    int* eidxp   = (int*)(ws + OFF_EIXP);
    float* sc1   = (float*)(ws + OFF_SC1);
    float* sb1   = (float*)(ws + OFF_SB1);
    float* sc2   = (float*)(ws + OFF_SC2);
    float* sb2   = (float*)(ws + OFF_SB2);

    hipMemsetAsync(ws + OFF_CNT, 0, ZERO_BYTES, stream);
    hipMemsetAsync(srcp, 0xFF, (size_t)CAP_SLOT * 4, stream);
    k_convert<<<4224, 256, 0, stream>>>(W_e, W1, W2, wet, w1t, w2t);
    k_hist<<<(NE + 255) / 256, 256, 0, stream>>>(ei + NE, counts);
    k_zero_heavy<<<(NN + 255) / 256, 256, 0, stream>>>(counts, aggr);
    k_scan1<<<NBLK_SCAN, 512, 0, stream>>>(counts, tex, bsum);
    k_scan2<<<1, 64, 0, stream>>>(bsum, boff, Tptr);
    k_scan3<<<NBLK_SCAN, 512, 0, stream>>>(counts, tex, boff, cursor, notile);
    k_scatter<<<(NE + 255) / 256, 256, 0, stream>>>(ei, ei + NE, cursor, srcp, eidxp);
    k_edge<<<CAP_TILE / 2, 256, 0, stream>>>(ea, wet, x, b_e, srcp, eidxp, notile, Tptr, aggr);
    k_combine<<<(int)(((long)NN * HD / 4 + 255) / 256), 256, 0, stream>>>(aggr, x, counts, eps, h);
    k_gemm_bn<true, false><<<dim3((NN + 127) / 128, H2 / 128), 256, 0, stream>>>(
        h, w1t, b1, h1, b1s, b1q, nullptr, nullptr, NN, HD, H2);
    k_bn_final<<<4, 256, 0, stream>>>(b1s, b1q, g1, beta1, sc1, sb1, H2, 1.f / NN);
    k_gemm_bn<false, true><<<dim3((NN + 127) / 128, HD / 128), 256, 0, stream>>>(
        h1, w2t, b2, out, b2s, b2q, sc1, sb1, NN, H2, HD);
    k_bn_final<<<2, 256, 0, stream>>>(b2s, b2q, g2, beta2, sc2, sb2, HD, 1.f / NN);
    k_out<<<(int)(((long)NN * HD / 4 + 255) / 256), 256, 0, stream>>>(out, sc2, sb2, (long)NN * HD);
}

// Round 3
// 996.404 us; speedup vs baseline: 1.1700x; 1.0846x over previous
//
#include <hip/hip_runtime.h>
#include <math.h>

#define NN 50000
#define NE 400000
#define HD 512
#define EDIM 64
#define H2 1024
#define LDT 72           // padded LDS row stride (ushorts)
#define CAP_SLOT 1200000 // padded edge-slot capacity (>= NE + 16*NN worst pad)
#define CAP_TILE 75000   // CAP_SLOT/16
#define CAP_HEAVY 8192   // max multi-tile (deg>16) nodes; expected ~200
#define NBLK_SCAN 98     // ceil(NN/512)

typedef short s16x8 __attribute__((ext_vector_type(8)));
typedef float f32x4 __attribute__((ext_vector_type(4)));

__device__ __forceinline__ unsigned short f2bf(float f) {
    union { float f; unsigned u; } v; v.f = f;
    unsigned r = v.u + 0x7fffu + ((v.u >> 16) & 1u);
    return (unsigned short)(r >> 16);
}
__device__ __forceinline__ float bf2f(unsigned short h) {
    union { unsigned u; float f; } v; v.u = ((unsigned)h) << 16;
    return v.f;
}
__device__ __forceinline__ float silu_f(float t) {
    return t / (1.f + __expf(-t));
}

// ---------------- workspace layout (bytes), total ~166.3 MB ----------------
// aggrc (compact heavy aggr) + xb live only until k_combine_heavy; h1 aliases both.
constexpr size_t OFF_AGGRC = 0;                       // f32 [CAP_HEAVY][512] = 16 MB (zeroed)
constexpr size_t OFF_XB   = 16777216;                 // bf16 [NN][512] interleaved = 51.2 MB
constexpr size_t OFF_H1   = 0;                        // bf16 [NN][1024] (aliases aggrc+xb, both dead)
constexpr size_t OFF_H    = 102400000;                // bf16 [NN][512]
constexpr size_t OFF_WET  = 153600000;                // bf16 [512][64]
constexpr size_t OFF_W1T  = OFF_WET + 65536;          // bf16 [1024][512]
constexpr size_t OFF_W2T  = OFF_W1T + 1048576;        // bf16 [512][1024]
constexpr size_t OFF_CNT  = OFF_W2T + 1048576;        // int[50000]   (zeroed)
constexpr size_t OFF_B1S  = OFF_CNT + 200000;         // float[1024]  (zeroed)
constexpr size_t OFF_B1Q  = OFF_B1S + 4096;           // float[1024]  (zeroed)
constexpr size_t OFF_B2S  = OFF_B1Q + 4096;           // float[512]   (zeroed)
constexpr size_t OFF_B2Q  = OFF_B2S + 2048;           // float[512]   (zeroed)
constexpr size_t ZERO_BYTES = 200000 + 4096 + 4096 + 2048 + 2048;
constexpr size_t OFF_TEX  = OFF_B2Q + 2048;           // int[50000] tile_excl -> hid map
constexpr size_t OFF_BSUM = OFF_TEX + 200000;         // int[128]
constexpr size_t OFF_BOFF = OFF_BSUM + 512;           // int[128]
constexpr size_t OFF_T    = OFF_BOFF + 512;           // int[16]: [0]=T, [1]=heavy counter
constexpr size_t OFF_CUR  = OFF_T + 64;               // int[50000]
constexpr size_t OFF_NOT  = OFF_CUR + 200000;         // int[75008] node_of_tile
constexpr size_t OFF_SRCP = OFF_NOT + 300032;         // int[CAP_SLOT] (memset 0xFF)
constexpr size_t OFF_EIXP = OFF_SRCP + 4800000;       // int[CAP_SLOT]
constexpr size_t OFF_SC1  = OFF_EIXP + 4800000;       // float[1024]
constexpr size_t OFF_SB1  = OFF_SC1 + 4096;           // float[1024]
constexpr size_t OFF_SC2  = OFF_SB1 + 4096;           // float[512]
constexpr size_t OFF_SB2  = OFF_SC2 + 2048;           // float[512]

// ---------------- weight transpose+convert to bf16 ----------------
__global__ __launch_bounds__(256) void k_convert(const float* __restrict__ We,
    const float* __restrict__ W1, const float* __restrict__ W2,
    unsigned short* __restrict__ wet, unsigned short* __restrict__ w1t,
    unsigned short* __restrict__ w2t) {
    int i = blockIdx.x * 256 + threadIdx.x;
    if (i < 32768) {
        int n = i >> 6, k = i & 63;
        wet[i] = f2bf(We[k * HD + n]);
    } else if (i < 32768 + 524288) {
        int j = i - 32768;
        int n = j >> 9, k = j & 511;
        w1t[j] = f2bf(W1[k * H2 + n]);
    } else if (i < 32768 + 2 * 524288) {
        int j = i - (32768 + 524288);
        int n = j >> 10, k = j & 1023;
        w2t[j] = f2bf(W2[k * HD + n]);
    }
}

// ---------------- x -> bf16, MFMA-gather-interleaved layout ----------------
// xb[n][cb*128 + l*8 + j] = x[n][cb*128 + j*16 + l]  (cb=colblock, l=lane&15, j=frag)
// so a lane's 8 columns {j*16+l} of a 128-col block are one contiguous 16B chunk.
__global__ __launch_bounds__(256) void k_xconv(const float* __restrict__ x,
    unsigned short* __restrict__ xb) {
    int t = blockIdx.x * 256 + threadIdx.x;   // NN*64 threads, 16B out each
    if (t >= NN * 64) return;
    int n = t >> 6, rem = t & 63;
    int cb = rem >> 4, l = rem & 15;
    const float* src = x + (size_t)n * HD + cb * 128 + l;
    unsigned short o[8];
    #pragma unroll
    for (int j = 0; j < 8; ++j) o[j] = f2bf(src[j * 16]);
    *(uint4*)(xb + (size_t)n * HD + cb * 128 + l * 8) = *(const uint4*)o;
}

// ---------------- histogram of dst ----------------
__global__ __launch_bounds__(256) void k_hist(const int* __restrict__ dst, int* __restrict__ counts) {
    int e = blockIdx.x * 256 + threadIdx.x;
    if (e < NE) atomicAdd(&counts[dst[e]], 1);
}

// ---------------- 3-phase scan of padded tile counts ----------------
__global__ __launch_bounds__(512) void k_scan1(const int* __restrict__ counts,
    int* __restrict__ tile_excl, int* __restrict__ bsum) {
    __shared__ int wsums[8];
    int b = blockIdx.x, t = threadIdx.x;
    int i = b * 512 + t;
    int v = (i < NN) ? ((counts[i] + 15) >> 4) : 0;   // tile count for node
    int lane = t & 63, wid = t >> 6;
    int x = v;
    #pragma unroll
    for (int o = 1; o < 64; o <<= 1) {
        int y = __shfl_up(x, o, 64);
        if (lane >= o) x += y;
    }
    if (lane == 63) wsums[wid] = x;
    __syncthreads();
    if (t == 0) {
        int run = 0;
        for (int w = 0; w < 8; ++w) { int tmp = wsums[w]; wsums[w] = run; run += tmp; }
    }
    __syncthreads();
    int excl = x - v + wsums[wid];
    if (i < NN) tile_excl[i] = excl;
    if (t == 511) bsum[b] = excl + v;
}

__global__ void k_scan2(const int* __restrict__ bsum, int* __restrict__ boff, int* __restrict__ Tout) {
    if (threadIdx.x == 0) {
        int run = 0;
        for (int b = 0; b < NBLK_SCAN; ++b) { boff[b] = run; run += bsum[b]; }
        Tout[0] = run;
        Tout[1] = 0;   // heavy-node counter
    }
}

// assigns compact heavy ids; repurposes tile_excl[i] as hid map after reading it
__global__ __launch_bounds__(512) void k_scan3(const int* __restrict__ counts,
    int* __restrict__ tile_excl, const int* __restrict__ boff,
    int* __restrict__ cursor, int* __restrict__ node_of_tile, int* __restrict__ Tout) {
    int b = blockIdx.x, t = threadIdx.x;
    int i = b * 512 + t;
    if (i >= NN) return;
    int tc = (counts[i] + 15) >> 4;
    int ts = tile_excl[i] + boff[b];
    cursor[i] = ts * 16;
    int hid = -1;
    if (tc > 1) {
        hid = atomicAdd(&Tout[1], 1);
        if (hid >= CAP_HEAVY) hid = CAP_HEAVY - 1;   // ~200 expected; never hit
    }
    tile_excl[i] = hid;   // hid map for k_combine_heavy
    unsigned tag = (tc > 1) ? (0x80000000u | (unsigned)hid) : (unsigned)i;
    for (int k = 0; k < tc; ++k) node_of_tile[ts + k] = (int)tag;
}

// ---------------- scatter edges into padded (ELL) slots ----------------
__global__ __launch_bounds__(256) void k_scatter(const int* __restrict__ src, const int* __restrict__ dst,
    int* __restrict__ cursor, int* __restrict__ srcp, int* __restrict__ eidxp) {
    int e = blockIdx.x * 256 + threadIdx.x;
    if (e < NE) {
        int d = dst[e];
        int p = atomicAdd(&cursor[d], 1);
        srcp[p] = src[e];
        eidxp[p] = e;
    }
}

// ---------------- fused edge GEMM + reduce + GIN combine (light nodes) ----------------
// block = 2 tiles x 512 cols, 4 waves (one 128-col block each).
// x gathered from interleaved bf16 xb: 1 dwordx4 per row instead of 8 strided dwords.
// Single-tile nodes (deg<=16, ~95%): full sum in regs -> write h=bf16((1+eps)x+sum) directly.
// Multi-tile nodes: atomicAdd into compact aggrc[hid].
__global__ __launch_bounds__(256, 4) void k_edge(
    const float* __restrict__ ea, const unsigned short* __restrict__ wet,
    const unsigned short* __restrict__ xb, const float* __restrict__ b_e,
    const float* __restrict__ eps,
    const int* __restrict__ srcp, const int* __restrict__ eidxp,
    const int* __restrict__ node_of_tile, const int* __restrict__ Tptr,
    float* __restrict__ aggrc, unsigned short* __restrict__ h) {
    int tile0 = blockIdx.x * 2;
    int T = Tptr[0];
    if (tile0 >= T) return;
    __shared__ unsigned short As[32 * LDT];   // 4.6 KB
    __shared__ int Ss[32];                    // srcp cache
    __shared__ float Rs[4][128];              // per-wave repack, 2 KB
    int t = threadIdx.x;
    int slot0 = tile0 * 16;
    // stage A: 32 gathered ea rows -> bf16 (zeros for pad slots); 8 threads/row
    {
        int r = t >> 3, qq = t & 7;
        int s = srcp[slot0 + r];
        if (qq == 0) Ss[r] = s;
        unsigned short* lp = As + r * LDT + qq * 8;
        if (s >= 0) {
            int eix = eidxp[slot0 + r];
            const float* gp = ea + (size_t)eix * EDIM + qq * 8;
            float4 v0 = ((const float4*)gp)[0];
            float4 v1 = ((const float4*)gp)[1];
            lp[0] = f2bf(v0.x); lp[1] = f2bf(v0.y); lp[2] = f2bf(v0.z); lp[3] = f2bf(v0.w);
            lp[4] = f2bf(v1.x); lp[5] = f2bf(v1.y); lp[6] = f2bf(v1.z); lp[7] = f2bf(v1.w);
        } else {
            uint4 z = {0u, 0u, 0u, 0u};
            *(uint4*)lp = z;
        }
    }
    __syncthreads();
    int wave = t >> 6, lane = t & 63, l15 = lane & 15, quad = lane >> 4;
    int cblk = wave * 128;
    f32x4 acc[2][8];
    #pragma unroll
    for (int i = 0; i < 2; ++i)
        #pragma unroll
        for (int j = 0; j < 8; ++j) acc[i][j] = (f32x4){0.f, 0.f, 0.f, 0.f};
    #pragma unroll
    for (int k0 = 0; k0 < 64; k0 += 32) {
        s16x8 af[2], bfr[8];
        #pragma unroll
        for (int i = 0; i < 2; ++i)
            af[i] = *(const s16x8*)(As + (i * 16 + l15) * LDT + k0 + quad * 8);
        #pragma unroll
        for (int j = 0; j < 8; ++j)
            bfr[j] = *(const s16x8*)(wet + (size_t)(cblk + j * 16 + l15) * EDIM + k0 + quad * 8);
        #pragma unroll
        for (int i = 0; i < 2; ++i)
            #pragma unroll
            for (int j = 0; j < 8; ++j)
                acc[i][j] = __builtin_amdgcn_mfma_f32_16x16x32_bf16(af[i], bfr[j], acc[i][j], 0, 0, 0);
    }
    float ep = 1.0f + eps[0];
    float bev[8];
    #pragma unroll
    for (int j = 0; j < 8; ++j) bev[j] = b_e[cblk + j * 16 + l15];
    float* rp = Rs[wave];
    #pragma unroll
    for (int i = 0; i < 2; ++i) {
        int tile = tile0 + i;
        unsigned meta = (unsigned)node_of_tile[tile];   // in-bounds; garbage ok if tile>=T
        int v = (int)(meta & 0x7fffffffu);              // node id (light) or hid (heavy)
        int vc = v < NN ? v : 0;                        // clamp for speculative load
        int srow = i * 16 + quad * 4;
        // gather: 4 rows x 16B (one dwordx4 each) + own row, all issued together
        s16x8 xr[4]; float msk[4];
        #pragma unroll
        for (int r = 0; r < 4; ++r) {
            int s = Ss[srow + r];
            msk[r] = s >= 0 ? 1.f : 0.f;
            xr[r] = *(const s16x8*)(xb + (size_t)(s >= 0 ? s : 0) * HD + cblk + l15 * 8);
        }
        s16x8 xo = *(const s16x8*)(xb + (size_t)vc * HD + cblk + l15 * 8);
        float sum8[8];
        #pragma unroll
        for (int j = 0; j < 8; ++j) sum8[j] = 0.f;
        #pragma unroll
        for (int r = 0; r < 4; ++r) {
            #pragma unroll
            for (int j = 0; j < 8; ++j) {
                float vv = acc[i][j][r] + bf2f((unsigned short)xr[r][j]) + bev[j];
                vv = vv > 0.f ? vv : 0.f;
                sum8[j] = fmaf(msk[r], vv, sum8[j]);
            }
        }
        #pragma unroll
        for (int j = 0; j < 8; ++j) {
            sum8[j] += __shfl_xor(sum8[j], 16, 64);
            sum8[j] += __shfl_xor(sum8[j], 32, 64);
        }
        if (tile < T) {
            if (meta & 0x80000000u) {
                if (quad == 0) {
                    float* ap = aggrc + (size_t)v * HD + cblk;
                    #pragma unroll
                    for (int j = 0; j < 8; ++j) atomicAdd(ap + j * 16 + l15, sum8[j]);
                }
            } else {
                // fused GIN combine: h = bf16(ep*x_v + sum); repack to 256B via LDS
                int j0 = quad * 2, j1 = j0 + 1;
                rp[j0 * 16 + l15] = fmaf(ep, bf2f((unsigned short)xo[j0]), sum8[j0]);
                rp[j1 * 16 + l15] = fmaf(ep, bf2f((unsigned short)xo[j1]), sum8[j1]);
                // same-wave DS ops complete in order; no barrier needed
                unsigned pk = (unsigned)f2bf(rp[lane * 2]) |
                              ((unsigned)f2bf(rp[lane * 2 + 1]) << 16);
                *(unsigned*)(h + (size_t)v * HD + cblk + lane * 2) = pk;
            }
        }
    }
}

// ---------------- finish heavy (deg>16) and deg-0 nodes ----------------
__global__ __launch_bounds__(256) void k_combine_heavy(const float* __restrict__ aggrc,
    const float* __restrict__ x, const int* __restrict__ counts, const int* __restrict__ hidmap,
    const float* __restrict__ eps, unsigned short* __restrict__ h) {
    long i = ((long)blockIdx.x * 256 + threadIdx.x) * 4;
    if (i >= (long)NN * HD) return;
    int v = (int)(i >> 9);
    int c = counts[v];
    if (c >= 1 && c <= 16) return;   // done in k_edge
    float ep = 1.0f + eps[0];
    float4 a = {0.f, 0.f, 0.f, 0.f};
    if (c > 16) a = *(const float4*)(aggrc + (size_t)hidmap[v] * HD + (i & (HD - 1)));
    float4 xv = *(const float4*)(x + i);
    uint2 p;
    p.x = (unsigned)f2bf(ep * xv.x + a.x) | ((unsigned)f2bf(ep * xv.y + a.y) << 16);
    p.y = (unsigned)f2bf(ep * xv.z + a.z) | ((unsigned)f2bf(ep * xv.w + a.w) << 16);
    *(uint2*)(h + i) = p;
}

// ---------------- bf16 GEMM + bias + BN column stats; optional fused SiLU-BN on A ----------------
template <bool BF16OUT, bool SILU_A>
__global__ __launch_bounds__(256) void k_gemm_bn(
    const unsigned short* __restrict__ A, const unsigned short* __restrict__ Bt,
    const float* __restrict__ bias, void* __restrict__ Cv,
    float* __restrict__ bn_sum, float* __restrict__ bn_sumsq,
    const float* __restrict__ a_sc, const float* __restrict__ a_sb,
    int M, int K, int Nn) {
    __shared__ unsigned short As[128 * LDT];
    __shared__ unsigned short Bs[128 * LDT];
    __shared__ float csum[128], csumsq[128];
    int mblk = blockIdx.x, nblk = blockIdx.y;
    int t = threadIdx.x;
    int row0 = mblk * 128, col0 = nblk * 128;
    int wid = t >> 6, lane = t & 63, l15 = lane & 15, quad = lane >> 4;
    f32x4 acc[2][8];
    #pragma unroll
    for (int i = 0; i < 2; ++i)
        #pragma unroll
        for (int j = 0; j < 8; ++j) acc[i][j] = (f32x4){0.f, 0.f, 0.f, 0.f};

    for (int k0 = 0; k0 < K; k0 += 64) {
        __syncthreads();
        {
            int r = t >> 1, half = t & 1;
            int row = row0 + r;
            int kb = k0 + half * 32;
            unsigned short* lp = As + r * LDT + half * 32;
            if (row < M) {
                const unsigned short* gp = A + (size_t)row * K + kb;
                if (SILU_A) {
                    #pragma unroll
                    for (int jj = 0; jj < 4; ++jj) {
                        uint4 u = *(const uint4*)(gp + jj * 8);
                        float4 sA = *(const float4*)(a_sc + kb + jj * 8);
                        float4 sB = *(const float4*)(a_sc + kb + jj * 8 + 4);
                        float4 bA = *(const float4*)(a_sb + kb + jj * 8);
                        float4 bB = *(const float4*)(a_sb + kb + jj * 8 + 4);
                        unsigned short o[8];
                        o[0] = f2bf(silu_f(bf2f((unsigned short)(u.x & 0xffffu)) * sA.x + bA.x));
                        o[1] = f2bf(silu_f(bf2f((unsigned short)(u.x >> 16)) * sA.y + bA.y));
                        o[2] = f2bf(silu_f(bf2f((unsigned short)(u.y & 0xffffu)) * sA.z + bA.z));
                        o[3] = f2bf(silu_f(bf2f((unsigned short)(u.y >> 16)) * sA.w + bA.w));
                        o[4] = f2bf(silu_f(bf2f((unsigned short)(u.z & 0xffffu)) * sB.x + bB.x));
                        o[5] = f2bf(silu_f(bf2f((unsigned short)(u.z >> 16)) * sB.y + bB.y));
                        o[6] = f2bf(silu_f(bf2f((unsigned short)(u.w & 0xffffu)) * sB.z + bB.z));
                        o[7] = f2bf(silu_f(bf2f((unsigned short)(u.w >> 16)) * sB.w + bB.w));
                        #pragma unroll
                        for (int m = 0; m < 8; ++m) lp[jj * 8 + m] = o[m];
                    }
                } else {
                    #pragma unroll
                    for (int jj = 0; jj < 4; ++jj) *(uint4*)(lp + jj * 8) = *(const uint4*)(gp + jj * 8);
                }
            } else {
                uint4 z = {0u, 0u, 0u, 0u};
                #pragma unroll
                for (int jj = 0; jj < 4; ++jj) *(uint4*)(lp + jj * 8) = z;
            }
            const unsigned short* gb = Bt + (size_t)(col0 + r) * K + kb;
            unsigned short* lb = Bs + r * LDT + half * 32;
            #pragma unroll
            for (int jj = 0; jj < 4; ++jj) *(uint4*)(lb + jj * 8) = *(const uint4*)(gb + jj * 8);
        }
        __syncthreads();
        #pragma unroll
        for (int kk = 0; kk < 64; kk += 32) {
            s16x8 af[2], bfr[8];
            #pragma unroll
            for (int i = 0; i < 2; ++i)
                af[i] = *(const s16x8*)(As + (wid * 32 + i * 16 + l15) * LDT + kk + quad * 8);
            #pragma unroll
            for (int j = 0; j < 8; ++j)
                bfr[j] = *(const s16x8*)(Bs + (j * 16 + l15) * LDT + kk + quad * 8);
            #pragma unroll
            for (int i = 0; i < 2; ++i)
                #pragma unroll
                for (int j = 0; j < 8; ++j)
                    acc[i][j] = __builtin_amdgcn_mfma_f32_16x16x32_bf16(af[i], bfr[j], acc[i][j], 0, 0, 0);
        }
    }
    if (t < 128) { csum[t] = 0.f; csumsq[t] = 0.f; }
    __syncthreads();
    int mrow0 = row0 + wid * 32;
    #pragma unroll
    for (int j = 0; j < 8; ++j) {
        int col = j * 16 + l15;
        float bv = bias[col0 + col];
        float ls = 0.f, lq = 0.f;
        #pragma unroll
        for (int i = 0; i < 2; ++i) {
            #pragma unroll
            for (int r = 0; r < 4; ++r) {
                int row = mrow0 + i * 16 + quad * 4 + r;
                if (row < M) {
                    float v = acc[i][j][r] + bv;
                    if (BF16OUT)
                        ((unsigned short*)Cv)[(size_t)row * Nn + col0 + col] = f2bf(v);
                    else
                        ((float*)Cv)[(size_t)row * Nn + col0 + col] = v;
                    ls += v; lq += v * v;
                }
            }
        }
        atomicAdd(&csum[col], ls);
        atomicAdd(&csumsq[col], lq);
    }
    __syncthreads();
    if (t < 128) {
        atomicAdd(bn_sum + col0 + t, csum[t]);
        atomicAdd(bn_sumsq + col0 + t, csumsq[t]);
    }
}

// ---------------- BN finalize ----------------
__global__ __launch_bounds__(256) void k_bn_final(const float* __restrict__ s,
    const float* __restrict__ q, const float* __restrict__ g, const float* __restrict__ beta,
    float* __restrict__ scale, float* __restrict__ sbias, int C, float invN) {
    int c = blockIdx.x * 256 + threadIdx.x;
    if (c < C) {
        float mu = s[c] * invN;
        float var = q[c] * invN - mu * mu;
        var = fmaxf(var, 0.f);
        float sc = g[c] * rsqrtf(var + 1e-5f);
        scale[c] = sc;
        sbias[c] = beta[c] - mu * sc;
    }
}

// ---------------- in-place out = silu(out*scale+bias) fp32 ----------------
__global__ __launch_bounds__(256) void k_out(float* __restrict__ out,
    const float* __restrict__ sc, const float* __restrict__ sb, long total) {
    long i = ((long)blockIdx.x * 256 + threadIdx.x) * 4;
    if (i >= total) return;
    int c = (int)(i & (HD - 1));
    float4 v = *(const float4*)(out + i);
    float4 s4 = *(const float4*)(sc + c);
    float4 b4 = *(const float4*)(sb + c);
    float4 o;
    o.x = silu_f(v.x * s4.x + b4.x);
    o.y = silu_f(v.y * s4.y + b4.y);
    o.z = silu_f(v.z * s4.z + b4.z);
    o.w = silu_f(v.w * s4.w + b4.w);
    *(float4*)(out + i) = o;
}

extern "C" void kernel_launch(void* const* d_in, const int* in_sizes, int n_in,
                              void* d_out, int out_size, void* d_ws, size_t ws_size,
                              hipStream_t stream) {
    const float* x      = (const float*)d_in[0];
    const float* ea     = (const float*)d_in[1];
    const int*   ei     = (const int*)d_in[2];     // [2][E]: src then dst
    const float* W_e    = (const float*)d_in[3];
    const float* b_e    = (const float*)d_in[4];
    const float* W1     = (const float*)d_in[5];
    const float* b1     = (const float*)d_in[6];
    const float* g1     = (const float*)d_in[7];
    const float* beta1  = (const float*)d_in[8];
    const float* W2     = (const float*)d_in[9];
    const float* b2     = (const float*)d_in[10];
    const float* g2     = (const float*)d_in[11];
    const float* beta2  = (const float*)d_in[12];
    const float* eps    = (const float*)d_in[13];
    float* out = (float*)d_out;
    char* ws = (char*)d_ws;

    float*          aggrc = (float*)(ws + OFF_AGGRC);
    unsigned short* xb   = (unsigned short*)(ws + OFF_XB);
    unsigned short* h1   = (unsigned short*)(ws + OFF_H1);   // aliases aggrc+xb (dead then)
    unsigned short* h    = (unsigned short*)(ws + OFF_H);
    unsigned short* wet  = (unsigned short*)(ws + OFF_WET);
    unsigned short* w1t  = (unsigned short*)(ws + OFF_W1T);
    unsigned short* w2t  = (unsigned short*)(ws + OFF_W2T);
    int* counts  = (int*)(ws + OFF_CNT);
    float* b1s   = (float*)(ws + OFF_B1S);
    float* b1q   = (float*)(ws + OFF_B1Q);
    float* b2s   = (float*)(ws + OFF_B2S);
    float* b2q   = (float*)(ws + OFF_B2Q);
    int* tex     = (int*)(ws + OFF_TEX);
    int* bsum    = (int*)(ws + OFF_BSUM);
    int* boff    = (int*)(ws + OFF_BOFF);
    int* Tptr    = (int*)(ws + OFF_T);
    int* cursor  = (int*)(ws + OFF_CUR);
    int* notile  = (int*)(ws + OFF_NOT);
    int* srcp    = (int*)(ws + OFF_SRCP);
    int* eidxp   = (int*)(ws + OFF_EIXP);
    float* sc1   = (float*)(ws + OFF_SC1);
    float* sb1   = (float*)(ws + OFF_SB1);
    float* sc2   = (float*)(ws + OFF_SC2);
    float* sb2   = (float*)(ws + OFF_SB2);

    hipMemsetAsync(aggrc, 0, (size_t)CAP_HEAVY * HD * 4, stream);
    hipMemsetAsync(ws + OFF_CNT, 0, ZERO_BYTES, stream);
    hipMemsetAsync(srcp, 0xFF, (size_t)CAP_SLOT * 4, stream);
    k_convert<<<4224, 256, 0, stream>>>(W_e, W1, W2, wet, w1t, w2t);
    k_xconv<<<(NN * 64 + 255) / 256, 256, 0, stream>>>(x, xb);
    k_hist<<<(NE + 255) / 256, 256, 0, stream>>>(ei + NE, counts);
    k_scan1<<<NBLK_SCAN, 512, 0, stream>>>(counts, tex, bsum);
    k_scan2<<<1, 64, 0, stream>>>(bsum, boff, Tptr);
    k_scan3<<<NBLK_SCAN, 512, 0, stream>>>(counts, tex, boff, cursor, notile, Tptr);
    k_scatter<<<(NE + 255) / 256, 256, 0, stream>>>(ei, ei + NE, cursor, srcp, eidxp);
    k_edge<<<CAP_TILE / 2, 256, 0, stream>>>(ea, wet, xb, b_e, eps, srcp, eidxp, notile, Tptr, aggrc, h);
    k_combine_heavy<<<(int)(((long)NN * HD / 4 + 255) / 256), 256, 0, stream>>>(
        aggrc, x, counts, tex, eps, h);
    k_gemm_bn<true, false><<<dim3((NN + 127) / 128, H2 / 128), 256, 0, stream>>>(
        h, w1t, b1, h1, b1s, b1q, nullptr, nullptr, NN, HD, H2);
    k_bn_final<<<4, 256, 0, stream>>>(b1s, b1q, g1, beta1, sc1, sb1, H2, 1.f / NN);
    k_gemm_bn<false, true><<<dim3((NN + 127) / 128, HD / 128), 256, 0, stream>>>(
        h1, w2t, b2, out, b2s, b2q, sc1, sb1, NN, H2, HD);
    k_bn_final<<<2, 256, 0, stream>>>(b2s, b2q, g2, beta2, sc2, sb2, HD, 1.f / NN);
    k_out<<<(int)(((long)NN * HD / 4 + 255) / 256), 256, 0, stream>>>(out, sc2, sb2, (long)NN * HD);
}